// Round 2
// baseline (274.182 us; speedup 1.0000x reference)
//
#include <hip/hip_runtime.h>
#include <hip/hip_bf16.h>
#include <cstdint>
#include <cstddef>
#include <type_traits>

// FocalAttention: B=4 T=2048 D=1024 H=16 hd=64 RADIUS=4 (banded attention, 9-wide window)
// fp32 in/out (per reference). Internally: fp32->bf16 convert, bf16 MFMA GEMMs, fp32 epilogue.
// Pipeline: [cvt x,Wqkv,Wproj] -> [GEMM1 qkv=x@Wqkv^T+b (bf16 out)] -> [banded attn (bf16)]
//           -> [GEMM2 out=a@Wproj^T+b (fp32 out)]

typedef __hip_bfloat16 bf16;
typedef __attribute__((ext_vector_type(8))) short bf16x8;   // A/B frag: 8 bf16 = 4 VGPRs
typedef __attribute__((ext_vector_type(4))) float f32x4;    // C/D frag
typedef __attribute__((ext_vector_type(8))) unsigned short u16x8;

#define BATCH  4
#define SEQ    2048
#define DIM    1024
#define NHEAD  16
#define HDIM   64
#define RADIUS 4
#define ROWS   (BATCH * SEQ)          // 8192
#define KDIM   1024

// --- async global->LDS, 16B per lane (wave-uniform LDS base + lane*16 layout).
__device__ __forceinline__ void async_copy16(const void* gptr, void* lptr) {
    __builtin_amdgcn_global_load_lds(
        (const __attribute__((address_space(1))) unsigned int*)(uintptr_t)gptr,
        (__attribute__((address_space(3))) unsigned int*)(uint32_t)(uintptr_t)lptr,
        16, 0, 0);
}

// fp32 -> bf16 convert, 8 elements/thread (two float4 loads, one 16B store).
__global__ __launch_bounds__(256)
void cvt_f32_bf16(const float* __restrict__ src, bf16* __restrict__ dst, int n8) {
    const int i = blockIdx.x * blockDim.x + threadIdx.x;
    if (i >= n8) return;
    const float4 a = ((const float4*)src)[2 * i];
    const float4 b = ((const float4*)src)[2 * i + 1];
    union { u16x8 v; __hip_bfloat16 h[8]; } o;
    o.h[0] = __float2bfloat16(a.x); o.h[1] = __float2bfloat16(a.y);
    o.h[2] = __float2bfloat16(a.z); o.h[3] = __float2bfloat16(a.w);
    o.h[4] = __float2bfloat16(b.x); o.h[5] = __float2bfloat16(b.y);
    o.h[6] = __float2bfloat16(b.z); o.h[7] = __float2bfloat16(b.w);
    ((u16x8*)dst)[i] = o.v;
}

// C[M,N] = A[M,K] * B[N,K]^T + bias[N]. A,B bf16; bias fp32; C = OutT (bf16 or fp32).
// Grid: (N/128, M/128), block 256 (4 waves, each 64x64 via 4x4 of 16x16x32 MFMA). K=1024.
template <int NMAT, typename OutT>
__global__ __launch_bounds__(256)
void gemm_bt_bias(const bf16* __restrict__ A, const bf16* __restrict__ B,
                  const float* __restrict__ bias, OutT* __restrict__ C) {
    __shared__ bf16 As[128 * 32];   // 8 KB, [row][k] contiguous (global_load_lds needs no padding)
    __shared__ bf16 Bs[128 * 32];

    const int tid  = threadIdx.x;
    const int lane = tid & 63;
    const int wave = tid >> 6;
    const int quad = lane >> 4;
    const int l16  = lane & 15;

    const int tileM = blockIdx.y * 128;
    const int tileN = blockIdx.x * 128;
    const int wm = (wave >> 1) * 64;
    const int wn = (wave & 1) * 64;

    f32x4 acc[4][4] = {};

    for (int kt = 0; kt < KDIM; kt += 32) {
        #pragma unroll
        for (int i = 0; i < 2; ++i) {
            const int chunk = i * 256 + tid;          // 0..511 -> 128 rows x 4 chunks of 16B
            const int row = chunk >> 2;
            const int cc  = chunk & 3;
            async_copy16(A + (size_t)(tileM + row) * KDIM + kt + cc * 8,
                         (char*)As + chunk * 16);
            async_copy16(B + (size_t)(tileN + row) * KDIM + kt + cc * 8,
                         (char*)Bs + chunk * 16);
        }
        __syncthreads();

        bf16x8 aF[4], bF[4];
        #pragma unroll
        for (int mt = 0; mt < 4; ++mt)
            aF[mt] = *(const bf16x8*)(As + (wm + mt * 16 + l16) * 32 + quad * 8);
        #pragma unroll
        for (int nt = 0; nt < 4; ++nt)
            bF[nt] = *(const bf16x8*)(Bs + (wn + nt * 16 + l16) * 32 + quad * 8);

        #pragma unroll
        for (int mt = 0; mt < 4; ++mt)
            #pragma unroll
            for (int nt = 0; nt < 4; ++nt)
                acc[mt][nt] = __builtin_amdgcn_mfma_f32_16x16x32_bf16(
                    aF[mt], bF[nt], acc[mt][nt], 0, 0, 0);
        __syncthreads();
    }

    // C/D layout: col = lane&15, row = quad*4 + reg  [m89/m91-verified]
    #pragma unroll
    for (int nt = 0; nt < 4; ++nt) {
        const int col = tileN + wn + nt * 16 + l16;
        const float bv = bias[col];
        #pragma unroll
        for (int mt = 0; mt < 4; ++mt) {
            #pragma unroll
            for (int r = 0; r < 4; ++r) {
                const int rowg = tileM + wm + mt * 16 + quad * 4 + r;
                const float v = acc[mt][nt][r] + bv;
                if constexpr (std::is_same<OutT, float>::value)
                    C[(size_t)rowg * NMAT + col] = v;
                else
                    C[(size_t)rowg * NMAT + col] = __float2bfloat16(v);
            }
        }
    }
}

// Banded attention: one wave per (b,h,t); lane = d in [0,64). qkv bf16 [row][s*1024+h*64+d].
__global__ __launch_bounds__(256)
void attn_banded(const bf16* __restrict__ qkv, bf16* __restrict__ aout) {
    const int gw   = (blockIdx.x * blockDim.x + threadIdx.x) >> 6;
    const int lane = threadIdx.x & 63;

    const int t  = gw & (SEQ - 1);
    const int bh = gw >> 11;
    const int h  = bh & (NHEAD - 1);
    const int b  = bh >> 4;

    const size_t rowbase = (size_t)b * SEQ * 3072;
    const int off = h * HDIM + lane;
    const float scale = 0.125f;

    const float q = __bfloat162float(qkv[rowbase + (size_t)t * 3072 + off]);

    float sc[2 * RADIUS + 1];
    float vv[2 * RADIUS + 1];
    #pragma unroll
    for (int j = 0; j < 2 * RADIUS + 1; ++j) {
        const int k = t - RADIUS + j;
        const bool valid = (k >= 0) && (k < SEQ);
        const int kc = valid ? k : t;
        const size_t kb = rowbase + (size_t)kc * 3072;
        const float kd = __bfloat162float(qkv[kb + 1024 + off]);
        vv[j] = __bfloat162float(qkv[kb + 2048 + off]);
        float p = q * kd;
        #pragma unroll
        for (int m = 32; m >= 1; m >>= 1) p += __shfl_xor(p, m, 64);
        sc[j] = valid ? p * scale : -1e30f;
    }

    float mx = sc[0];
    #pragma unroll
    for (int j = 1; j < 2 * RADIUS + 1; ++j) mx = fmaxf(mx, sc[j]);
    float sum = 0.f, acc = 0.f;
    #pragma unroll
    for (int j = 0; j < 2 * RADIUS + 1; ++j) {
        const float e = __expf(sc[j] - mx);
        sum += e;
        acc += e * vv[j];
    }
    aout[(size_t)(b * SEQ + t) * DIM + off] = __float2bfloat16(acc / sum);
}

extern "C" void kernel_launch(void* const* d_in, const int* in_sizes, int n_in,
                              void* d_out, int out_size, void* d_ws, size_t ws_size,
                              hipStream_t stream) {
    const float* x      = (const float*)d_in[0];  // [4,2048,1024] fp32
    const float* w_qkv  = (const float*)d_in[1];  // [3072,1024]
    const float* b_qkv  = (const float*)d_in[2];  // [3072]
    const float* w_proj = (const float*)d_in[3];  // [1024,1024]
    const float* b_proj = (const float*)d_in[4];  // [1024]
    float* out = (float*)d_out;                   // [4,2048,1024] fp32

    // workspace layout (bf16): xb 16MiB | wqkvb 6MiB | wprojb 2MiB | qkvb 48MiB | attnb 16MiB
    bf16* xb     = (bf16*)d_ws;
    bf16* wqkvb  = xb + (size_t)ROWS * DIM;
    bf16* wprojb = wqkvb + (size_t)3072 * 1024;
    bf16* qkvb   = wprojb + (size_t)1024 * 1024;
    bf16* attnb  = qkvb + (size_t)ROWS * 3072;

    // fp32 -> bf16 converts (8 elems/thread)
    cvt_f32_bf16<<<(ROWS * DIM / 8 + 255) / 256, 256, 0, stream>>>(x, xb, ROWS * DIM / 8);
    cvt_f32_bf16<<<(3072 * 1024 / 8 + 255) / 256, 256, 0, stream>>>(w_qkv, wqkvb, 3072 * 1024 / 8);
    cvt_f32_bf16<<<(1024 * 1024 / 8 + 255) / 256, 256, 0, stream>>>(w_proj, wprojb, 1024 * 1024 / 8);

    // GEMM1: qkvb[8192,3072] = xb @ wqkvb^T + b_qkv
    gemm_bt_bias<3072, bf16><<<dim3(3072 / 128, ROWS / 128), 256, 0, stream>>>(xb, wqkvb, b_qkv, qkvb);

    // Banded attention: 131072 waves, 4 waves/block
    attn_banded<<<(BATCH * NHEAD * SEQ) / 4, 256, 0, stream>>>(qkvb, attnb);

    // GEMM2: out[8192,1024] = attnb @ wprojb^T + b_proj  (fp32 out)
    gemm_bt_bias<1024, float><<<dim3(1024 / 128, ROWS / 128), 256, 0, stream>>>(attnb, wprojb, b_proj, out);
}

// Round 3
// 226.183 us; speedup vs baseline: 1.2122x; 1.2122x over previous
//
#include <hip/hip_runtime.h>
#include <hip/hip_bf16.h>
#include <cstdint>
#include <cstddef>
#include <type_traits>

// FocalAttention: B=4 T=2048 D=1024 H=16 hd=64 RADIUS=4 (banded, 9-wide window)
// fp32 in/out. Internally: fused fp32->bf16 convert, bf16 MFMA GEMMs, thread-per-half-query
// banded attention (no wave reductions), fp32 epilogue.

typedef __hip_bfloat16 bf16;
typedef __attribute__((ext_vector_type(8))) short bf16x8;   // A/B frag: 8 bf16 = 4 VGPRs
typedef __attribute__((ext_vector_type(4))) float f32x4;    // C/D frag
typedef __attribute__((ext_vector_type(8))) unsigned short u16x8;

#define BATCH  4
#define SEQ    2048
#define DIM    1024
#define NHEAD  16
#define HDIM   64
#define RADIUS 4
#define ROWS   (BATCH * SEQ)          // 8192
#define KDIM   1024

// --- async global->LDS, 16B per lane (wave-uniform LDS base + lane*16 layout).
__device__ __forceinline__ void async_copy16(const void* gptr, void* lptr) {
    __builtin_amdgcn_global_load_lds(
        (const __attribute__((address_space(1))) unsigned int*)(uintptr_t)gptr,
        (__attribute__((address_space(3))) unsigned int*)(uint32_t)(uintptr_t)lptr,
        16, 0, 0);
}

// Fused fp32 -> bf16 convert for all three tensors, 8 elems/thread.
__global__ __launch_bounds__(256)
void cvt_all(const float* __restrict__ s1, bf16* __restrict__ d1, int n1,
             const float* __restrict__ s2, bf16* __restrict__ d2, int n2,
             const float* __restrict__ s3, bf16* __restrict__ d3, int n3) {
    int i = blockIdx.x * blockDim.x + threadIdx.x;
    const float* src; bf16* dst;
    if (i < n1)              { src = s1; dst = d1; }
    else if (i < n1 + n2)    { i -= n1; src = s2; dst = d2; }
    else if (i < n1+n2+n3)   { i -= n1 + n2; src = s3; dst = d3; }
    else return;
    const float4 a = ((const float4*)src)[2 * i];
    const float4 b = ((const float4*)src)[2 * i + 1];
    union { u16x8 v; __hip_bfloat16 h[8]; } o;
    o.h[0] = __float2bfloat16(a.x); o.h[1] = __float2bfloat16(a.y);
    o.h[2] = __float2bfloat16(a.z); o.h[3] = __float2bfloat16(a.w);
    o.h[4] = __float2bfloat16(b.x); o.h[5] = __float2bfloat16(b.y);
    o.h[6] = __float2bfloat16(b.z); o.h[7] = __float2bfloat16(b.w);
    ((u16x8*)dst)[i] = o.v;
}

// C[M,N] = A[M,K] * B[N,K]^T + bias[N]. A,B bf16; bias fp32; C = OutT (bf16 or fp32).
template <int NMAT, typename OutT>
__global__ __launch_bounds__(256)
void gemm_bt_bias(const bf16* __restrict__ A, const bf16* __restrict__ B,
                  const float* __restrict__ bias, OutT* __restrict__ C) {
    __shared__ bf16 As[128 * 32];
    __shared__ bf16 Bs[128 * 32];

    const int tid  = threadIdx.x;
    const int lane = tid & 63;
    const int wave = tid >> 6;
    const int quad = lane >> 4;
    const int l16  = lane & 15;

    const int tileM = blockIdx.y * 128;
    const int tileN = blockIdx.x * 128;
    const int wm = (wave >> 1) * 64;
    const int wn = (wave & 1) * 64;

    f32x4 acc[4][4] = {};

    for (int kt = 0; kt < KDIM; kt += 32) {
        #pragma unroll
        for (int i = 0; i < 2; ++i) {
            const int chunk = i * 256 + tid;
            const int row = chunk >> 2;
            const int cc  = chunk & 3;
            async_copy16(A + (size_t)(tileM + row) * KDIM + kt + cc * 8,
                         (char*)As + chunk * 16);
            async_copy16(B + (size_t)(tileN + row) * KDIM + kt + cc * 8,
                         (char*)Bs + chunk * 16);
        }
        __syncthreads();

        bf16x8 aF[4], bF[4];
        #pragma unroll
        for (int mt = 0; mt < 4; ++mt)
            aF[mt] = *(const bf16x8*)(As + (wm + mt * 16 + l16) * 32 + quad * 8);
        #pragma unroll
        for (int nt = 0; nt < 4; ++nt)
            bF[nt] = *(const bf16x8*)(Bs + (wn + nt * 16 + l16) * 32 + quad * 8);

        #pragma unroll
        for (int mt = 0; mt < 4; ++mt)
            #pragma unroll
            for (int nt = 0; nt < 4; ++nt)
                acc[mt][nt] = __builtin_amdgcn_mfma_f32_16x16x32_bf16(
                    aF[mt], bF[nt], acc[mt][nt], 0, 0, 0);
        __syncthreads();
    }

    #pragma unroll
    for (int nt = 0; nt < 4; ++nt) {
        const int col = tileN + wn + nt * 16 + l16;
        const float bv = bias[col];
        #pragma unroll
        for (int mt = 0; mt < 4; ++mt) {
            #pragma unroll
            for (int r = 0; r < 4; ++r) {
                const int rowg = tileM + wm + mt * 16 + quad * 4 + r;
                const float v = acc[mt][nt][r] + bv;
                if constexpr (std::is_same<OutT, float>::value)
                    C[(size_t)rowg * NMAT + col] = v;
                else
                    C[(size_t)rowg * NMAT + col] = __float2bfloat16(v);
            }
        }
    }
}

// ---- 8 bf16 (as uint4) -> 8 floats (hi half = mask, lo half = shift)
__device__ __forceinline__ void bf8_to_f32(const uint4 u, float* f) {
    union { uint32_t u; float f; } c;
    c.u = u.x << 16;         f[0] = c.f;
    c.u = u.x & 0xffff0000u; f[1] = c.f;
    c.u = u.y << 16;         f[2] = c.f;
    c.u = u.y & 0xffff0000u; f[3] = c.f;
    c.u = u.z << 16;         f[4] = c.f;
    c.u = u.z & 0xffff0000u; f[5] = c.f;
    c.u = u.w << 16;         f[6] = c.f;
    c.u = u.w & 0xffff0000u; f[7] = c.f;
}

// Banded attention, thread-per-half-query. Block=256 threads covers 128 queries
// of one (b,h). tid = qi*2 + hf: qi in [0,128), hf in {0,1} selects 32 dims.
// qkv layout: [b*T+t][ s*1024 + h*64 + d ]. Scores merged across halves via shfl_xor(1).
__global__ __launch_bounds__(256)
void attn_banded2(const bf16* __restrict__ qkv, bf16* __restrict__ aout) {
    const int tid = threadIdx.x;
    const int qi  = tid >> 1;
    const int hf  = tid & 1;
    const int t0  = blockIdx.x * 128;
    const int h   = blockIdx.y;
    const int b   = blockIdx.z;
    const int t   = t0 + qi;

    const size_t rowstride = 3072;
    const size_t base = ((size_t)b * SEQ + t) * rowstride + h * HDIM + hf * 32;
    const float scale = 0.125f;   // hd^-0.5

    // ---- load q half (32 bf16 = 4x16B), convert to f32
    float q32[32];
    {
        const uint4* qp = (const uint4*)(qkv + base);
        uint4 u0 = qp[0], u1 = qp[1], u2 = qp[2], u3 = qp[3];
        bf8_to_f32(u0, q32 + 0);  bf8_to_f32(u1, q32 + 8);
        bf8_to_f32(u2, q32 + 16); bf8_to_f32(u3, q32 + 24);
    }

    // ---- pass 1: 9 banded scores (32-dim partial dot per thread)
    float sc[2 * RADIUS + 1];
    #pragma unroll
    for (int j = 0; j < 2 * RADIUS + 1; ++j) {
        const int k = t - RADIUS + j;
        const bool valid = (k >= 0) && (k < SEQ);
        const int kc = valid ? k : t;
        const uint4* kp = (const uint4*)(qkv + base + ((size_t)(kc - t)) * rowstride + 1024);
        float kf[32];
        uint4 u0 = kp[0], u1 = kp[1], u2 = kp[2], u3 = kp[3];
        bf8_to_f32(u0, kf + 0);  bf8_to_f32(u1, kf + 8);
        bf8_to_f32(u2, kf + 16); bf8_to_f32(u3, kf + 24);
        float p = 0.f;
        #pragma unroll
        for (int e = 0; e < 32; ++e) p = fmaf(q32[e], kf[e], p);
        p += __shfl_xor(p, 1, 64);          // merge the two 32-dim halves
        sc[j] = valid ? p * scale : -1e30f;
    }

    // ---- softmax over 9 scores
    float mx = sc[0];
    #pragma unroll
    for (int j = 1; j < 2 * RADIUS + 1; ++j) mx = fmaxf(mx, sc[j]);
    float sum = 0.f;
    #pragma unroll
    for (int j = 0; j < 2 * RADIUS + 1; ++j) { sc[j] = __expf(sc[j] - mx); sum += sc[j]; }
    const float inv = 1.0f / sum;

    // ---- pass 2: weighted V accumulation (32 dims per thread)
    float o32[32];
    #pragma unroll
    for (int e = 0; e < 32; ++e) o32[e] = 0.f;
    #pragma unroll
    for (int j = 0; j < 2 * RADIUS + 1; ++j) {
        const int k = t - RADIUS + j;
        const int kc = (k >= 0 && k < SEQ) ? k : t;   // weight ~0 when clamped
        const uint4* vp = (const uint4*)(qkv + base + ((size_t)(kc - t)) * rowstride + 2048);
        float vf[32];
        uint4 u0 = vp[0], u1 = vp[1], u2 = vp[2], u3 = vp[3];
        bf8_to_f32(u0, vf + 0);  bf8_to_f32(u1, vf + 8);
        bf8_to_f32(u2, vf + 16); bf8_to_f32(u3, vf + 24);
        const float w = sc[j];
        #pragma unroll
        for (int e = 0; e < 32; ++e) o32[e] = fmaf(w, vf[e], o32[e]);
    }

    // ---- store 32 bf16 (4x8)
    bf16* op = aout + ((size_t)b * SEQ + t) * DIM + h * HDIM + hf * 32;
    #pragma unroll
    for (int c = 0; c < 4; ++c) {
        union { u16x8 v; __hip_bfloat16 hh[8]; } o;
        #pragma unroll
        for (int e = 0; e < 8; ++e) o.hh[e] = __float2bfloat16(o32[c * 8 + e] * inv);
        ((u16x8*)op)[c] = o.v;
    }
}

extern "C" void kernel_launch(void* const* d_in, const int* in_sizes, int n_in,
                              void* d_out, int out_size, void* d_ws, size_t ws_size,
                              hipStream_t stream) {
    const float* x      = (const float*)d_in[0];
    const float* w_qkv  = (const float*)d_in[1];
    const float* b_qkv  = (const float*)d_in[2];
    const float* w_proj = (const float*)d_in[3];
    const float* b_proj = (const float*)d_in[4];
    float* out = (float*)d_out;

    bf16* xb     = (bf16*)d_ws;
    bf16* wqkvb  = xb + (size_t)ROWS * DIM;
    bf16* wprojb = wqkvb + (size_t)3072 * 1024;
    bf16* qkvb   = wprojb + (size_t)1024 * 1024;
    bf16* attnb  = qkvb + (size_t)ROWS * 3072;

    const int n1 = ROWS * DIM / 8, n2 = 3072 * 1024 / 8, n3 = 1024 * 1024 / 8;
    cvt_all<<<(n1 + n2 + n3 + 255) / 256, 256, 0, stream>>>(x, xb, n1, w_qkv, wqkvb, n2,
                                                            w_proj, wprojb, n3);

    gemm_bt_bias<3072, bf16><<<dim3(3072 / 128, ROWS / 128), 256, 0, stream>>>(xb, wqkvb, b_qkv, qkvb);

    attn_banded2<<<dim3(SEQ / 128, NHEAD, BATCH), 256, 0, stream>>>(qkvb, attnb);

    gemm_bt_bias<1024, float><<<dim3(1024 / 128, ROWS / 128), 256, 0, stream>>>(attnb, wprojb, b_proj, out);
}

// Round 4
// 226.037 us; speedup vs baseline: 1.2130x; 1.0006x over previous
//
#include <hip/hip_runtime.h>
#include <hip/hip_bf16.h>
#include <cstdint>
#include <cstddef>
#include <type_traits>

// FocalAttention: B=4 T=2048 D=1024 H=16 hd=64 RADIUS=4 (banded, 9-wide window)
// fp32 in/out. fused fp32->bf16 convert -> bf16 MFMA GEMM1 -> banded attn -> GEMM2 (fp32 out).
// GEMM: 128x128 tile, BK=64, XOR-swizzled LDS (kills the 8-way ds_read_b128 bank conflict
// of the naive 64/128-B-row layout while keeping global_load_lds lane-contiguous dests).

typedef __hip_bfloat16 bf16;
typedef __attribute__((ext_vector_type(8))) short bf16x8;   // A/B frag: 8 bf16 = 4 VGPRs
typedef __attribute__((ext_vector_type(4))) float f32x4;    // C/D frag
typedef __attribute__((ext_vector_type(8))) unsigned short u16x8;

#define BATCH  4
#define SEQ    2048
#define DIM    1024
#define NHEAD  16
#define HDIM   64
#define RADIUS 4
#define ROWS   (BATCH * SEQ)          // 8192
#define KDIM   1024

// --- async global->LDS, 16B per lane (LDS dest must be wave-uniform base + lane*16;
//     the GLOBAL address is per-lane free -> we exploit that for the XOR swizzle).
__device__ __forceinline__ void async_copy16(const void* gptr, void* lptr) {
    __builtin_amdgcn_global_load_lds(
        (const __attribute__((address_space(1))) unsigned int*)(uintptr_t)gptr,
        (__attribute__((address_space(3))) unsigned int*)(uint32_t)(uintptr_t)lptr,
        16, 0, 0);
}

// Fused fp32 -> bf16 convert for all three tensors, 8 elems/thread.
__global__ __launch_bounds__(256)
void cvt_all(const float* __restrict__ s1, bf16* __restrict__ d1, int n1,
             const float* __restrict__ s2, bf16* __restrict__ d2, int n2,
             const float* __restrict__ s3, bf16* __restrict__ d3, int n3) {
    int i = blockIdx.x * blockDim.x + threadIdx.x;
    const float* src; bf16* dst;
    if (i < n1)              { src = s1; dst = d1; }
    else if (i < n1 + n2)    { i -= n1; src = s2; dst = d2; }
    else if (i < n1+n2+n3)   { i -= n1 + n2; src = s3; dst = d3; }
    else return;
    const float4 a = ((const float4*)src)[2 * i];
    const float4 b = ((const float4*)src)[2 * i + 1];
    union { u16x8 v; __hip_bfloat16 h[8]; } o;
    o.h[0] = __float2bfloat16(a.x); o.h[1] = __float2bfloat16(a.y);
    o.h[2] = __float2bfloat16(a.z); o.h[3] = __float2bfloat16(a.w);
    o.h[4] = __float2bfloat16(b.x); o.h[5] = __float2bfloat16(b.y);
    o.h[6] = __float2bfloat16(b.z); o.h[7] = __float2bfloat16(b.w);
    ((u16x8*)dst)[i] = o.v;
}

// C[M,N] = A[M,K] * B[N,K]^T + bias[N]. A,B bf16; bias fp32; C = OutT (bf16 or fp32).
// BK=64: LDS rows are 128 B = 8 x 16-B chunks; chunk kc of row r is stored at LDS slot
// (kc ^ (r & 7)). ds_read bank group becomes (kc ^ (l16 & 7)) -> 16 lanes spread 2-way
// over 8 bank groups = conflict-free (m136: 2-way free).
template <int NMAT, typename OutT>
__global__ __launch_bounds__(256)
void gemm_bt_bias(const bf16* __restrict__ A, const bf16* __restrict__ B,
                  const float* __restrict__ bias, OutT* __restrict__ C) {
    __shared__ bf16 As[128 * 64];   // 16 KB
    __shared__ bf16 Bs[128 * 64];   // 16 KB

    const int tid  = threadIdx.x;
    const int lane = tid & 63;
    const int wave = tid >> 6;
    const int quad = lane >> 4;
    const int l16  = lane & 15;

    const int tileM = blockIdx.y * 128;
    const int tileN = blockIdx.x * 128;
    const int wm = (wave >> 1) * 64;
    const int wn = (wave & 1) * 64;

    f32x4 acc[4][4] = {};

    for (int kt = 0; kt < KDIM; kt += 64) {
        // ---- stage 128x64 tiles: 1024 chunks of 16 B each, 4 per thread per matrix.
        // LDS slot c holds global chunk (c&7) ^ (row&7) of row c>>3.
        #pragma unroll
        for (int i = 0; i < 4; ++i) {
            const int c   = i * 256 + tid;       // LDS chunk index, lane-contiguous per wave
            const int row = c >> 3;              // 0..127
            const int kg  = (c & 7) ^ (row & 7); // swizzled global chunk
            async_copy16(A + (size_t)(tileM + row) * KDIM + kt + kg * 8,
                         (char*)As + c * 16);
            async_copy16(B + (size_t)(tileN + row) * KDIM + kt + kg * 8,
                         (char*)Bs + c * 16);
        }
        __syncthreads();

        // ---- two k-steps of 32: frag chunk kq = ks*4+quad, de-swizzle with l16&7
        #pragma unroll
        for (int ks = 0; ks < 2; ++ks) {
            const int kq = ks * 4 + quad;
            const int so = (kq ^ (l16 & 7)) * 8;   // element offset within the 64-elem row
            bf16x8 aF[4], bF[4];
            #pragma unroll
            for (int mt = 0; mt < 4; ++mt)
                aF[mt] = *(const bf16x8*)(As + (wm + mt * 16 + l16) * 64 + so);
            #pragma unroll
            for (int nt = 0; nt < 4; ++nt)
                bF[nt] = *(const bf16x8*)(Bs + (wn + nt * 16 + l16) * 64 + so);

            #pragma unroll
            for (int mt = 0; mt < 4; ++mt)
                #pragma unroll
                for (int nt = 0; nt < 4; ++nt)
                    acc[mt][nt] = __builtin_amdgcn_mfma_f32_16x16x32_bf16(
                        aF[mt], bF[nt], acc[mt][nt], 0, 0, 0);
        }
        __syncthreads();
    }

    // ---- epilogue: C/D layout col = lane&15, row = quad*4 + reg  [m89/m91-verified]
    #pragma unroll
    for (int nt = 0; nt < 4; ++nt) {
        const int col = tileN + wn + nt * 16 + l16;
        const float bv = bias[col];
        #pragma unroll
        for (int mt = 0; mt < 4; ++mt) {
            #pragma unroll
            for (int r = 0; r < 4; ++r) {
                const int rowg = tileM + wm + mt * 16 + quad * 4 + r;
                const float v = acc[mt][nt][r] + bv;
                if constexpr (std::is_same<OutT, float>::value)
                    C[(size_t)rowg * NMAT + col] = v;
                else
                    C[(size_t)rowg * NMAT + col] = __float2bfloat16(v);
            }
        }
    }
}

// ---- 8 bf16 (as uint4) -> 8 floats (hi half = mask, lo half = shift)
__device__ __forceinline__ void bf8_to_f32(const uint4 u, float* f) {
    union { uint32_t u; float f; } c;
    c.u = u.x << 16;         f[0] = c.f;
    c.u = u.x & 0xffff0000u; f[1] = c.f;
    c.u = u.y << 16;         f[2] = c.f;
    c.u = u.y & 0xffff0000u; f[3] = c.f;
    c.u = u.z << 16;         f[4] = c.f;
    c.u = u.z & 0xffff0000u; f[5] = c.f;
    c.u = u.w << 16;         f[6] = c.f;
    c.u = u.w & 0xffff0000u; f[7] = c.f;
}

// Banded attention, thread-per-half-query. Block=256 covers 128 queries of one (b,h).
__global__ __launch_bounds__(256)
void attn_banded2(const bf16* __restrict__ qkv, bf16* __restrict__ aout) {
    const int tid = threadIdx.x;
    const int qi  = tid >> 1;
    const int hf  = tid & 1;
    const int t0  = blockIdx.x * 128;
    const int h   = blockIdx.y;
    const int b   = blockIdx.z;
    const int t   = t0 + qi;

    const size_t rowstride = 3072;
    const size_t base = ((size_t)b * SEQ + t) * rowstride + h * HDIM + hf * 32;
    const float scale = 0.125f;

    float q32[32];
    {
        const uint4* qp = (const uint4*)(qkv + base);
        uint4 u0 = qp[0], u1 = qp[1], u2 = qp[2], u3 = qp[3];
        bf8_to_f32(u0, q32 + 0);  bf8_to_f32(u1, q32 + 8);
        bf8_to_f32(u2, q32 + 16); bf8_to_f32(u3, q32 + 24);
    }

    float sc[2 * RADIUS + 1];
    #pragma unroll
    for (int j = 0; j < 2 * RADIUS + 1; ++j) {
        const int k = t - RADIUS + j;
        const bool valid = (k >= 0) && (k < SEQ);
        const int kc = valid ? k : t;
        const uint4* kp = (const uint4*)(qkv + base + ((size_t)(kc - t)) * rowstride + 1024);
        float kf[32];
        uint4 u0 = kp[0], u1 = kp[1], u2 = kp[2], u3 = kp[3];
        bf8_to_f32(u0, kf + 0);  bf8_to_f32(u1, kf + 8);
        bf8_to_f32(u2, kf + 16); bf8_to_f32(u3, kf + 24);
        float p = 0.f;
        #pragma unroll
        for (int e = 0; e < 32; ++e) p = fmaf(q32[e], kf[e], p);
        p += __shfl_xor(p, 1, 64);
        sc[j] = valid ? p * scale : -1e30f;
    }

    float mx = sc[0];
    #pragma unroll
    for (int j = 1; j < 2 * RADIUS + 1; ++j) mx = fmaxf(mx, sc[j]);
    float sum = 0.f;
    #pragma unroll
    for (int j = 0; j < 2 * RADIUS + 1; ++j) { sc[j] = __expf(sc[j] - mx); sum += sc[j]; }
    const float inv = 1.0f / sum;

    float o32[32];
    #pragma unroll
    for (int e = 0; e < 32; ++e) o32[e] = 0.f;
    #pragma unroll
    for (int j = 0; j < 2 * RADIUS + 1; ++j) {
        const int k = t - RADIUS + j;
        const int kc = (k >= 0 && k < SEQ) ? k : t;
        const uint4* vp = (const uint4*)(qkv + base + ((size_t)(kc - t)) * rowstride + 2048);
        float vf[32];
        uint4 u0 = vp[0], u1 = vp[1], u2 = vp[2], u3 = vp[3];
        bf8_to_f32(u0, vf + 0);  bf8_to_f32(u1, vf + 8);
        bf8_to_f32(u2, vf + 16); bf8_to_f32(u3, vf + 24);
        const float w = sc[j];
        #pragma unroll
        for (int e = 0; e < 32; ++e) o32[e] = fmaf(w, vf[e], o32[e]);
    }

    bf16* op = aout + ((size_t)b * SEQ + t) * DIM + h * HDIM + hf * 32;
    #pragma unroll
    for (int c = 0; c < 4; ++c) {
        union { u16x8 v; __hip_bfloat16 hh[8]; } o;
        #pragma unroll
        for (int e = 0; e < 8; ++e) o.hh[e] = __float2bfloat16(o32[c * 8 + e] * inv);
        ((u16x8*)op)[c] = o.v;
    }
}

extern "C" void kernel_launch(void* const* d_in, const int* in_sizes, int n_in,
                              void* d_out, int out_size, void* d_ws, size_t ws_size,
                              hipStream_t stream) {
    const float* x      = (const float*)d_in[0];
    const float* w_qkv  = (const float*)d_in[1];
    const float* b_qkv  = (const float*)d_in[2];
    const float* w_proj = (const float*)d_in[3];
    const float* b_proj = (const float*)d_in[4];
    float* out = (float*)d_out;

    bf16* xb     = (bf16*)d_ws;
    bf16* wqkvb  = xb + (size_t)ROWS * DIM;
    bf16* wprojb = wqkvb + (size_t)3072 * 1024;
    bf16* qkvb   = wprojb + (size_t)1024 * 1024;
    bf16* attnb  = qkvb + (size_t)ROWS * 3072;

    const int n1 = ROWS * DIM / 8, n2 = 3072 * 1024 / 8, n3 = 1024 * 1024 / 8;
    cvt_all<<<(n1 + n2 + n3 + 255) / 256, 256, 0, stream>>>(x, xb, n1, w_qkv, wqkvb, n2,
                                                            w_proj, wprojb, n3);

    gemm_bt_bias<3072, bf16><<<dim3(3072 / 128, ROWS / 128), 256, 0, stream>>>(xb, wqkvb, b_qkv, qkvb);

    attn_banded2<<<dim3(SEQ / 128, NHEAD, BATCH), 256, 0, stream>>>(qkvb, attnb);

    gemm_bt_bias<1024, float><<<dim3(1024 / 128, ROWS / 128), 256, 0, stream>>>(attnb, wprojb, b_proj, out);
}

// Round 5
// 222.845 us; speedup vs baseline: 1.2304x; 1.0143x over previous
//
#include <hip/hip_runtime.h>
#include <hip/hip_bf16.h>
#include <cstdint>
#include <cstddef>
#include <type_traits>

// FocalAttention: B=4 T=2048 D=1024 H=16 hd=64 RADIUS=4 (banded, 9-wide window)
// fp32 in/out. cvt(fp32->bf16) -> GEMM1 (writes qkv in [b,h,s,t,d] attention-native
// layout) -> banded attn (sequential-stream reads) -> GEMM2 (fp32 out).
// GEMM: 128x128 tile, BK=64, XOR-swizzled LDS (0 bank conflicts, verified r4).

typedef __hip_bfloat16 bf16;
typedef __attribute__((ext_vector_type(8))) short bf16x8;   // A/B frag: 8 bf16 = 4 VGPRs
typedef __attribute__((ext_vector_type(4))) float f32x4;    // C/D frag
typedef __attribute__((ext_vector_type(8))) unsigned short u16x8;

#define BATCH  4
#define SEQ    2048
#define DIM    1024
#define NHEAD  16
#define HDIM   64
#define RADIUS 4
#define ROWS   (BATCH * SEQ)          // 8192
#define KDIM   1024
#define HSLICE (SEQ * HDIM)           // 131072 elems per (b,h,s) slice

// --- async global->LDS, 16B per lane (LDS dest wave-uniform base + lane*16; the GLOBAL
//     address is per-lane free -> exploited for the XOR swizzle).
__device__ __forceinline__ void async_copy16(const void* gptr, void* lptr) {
    __builtin_amdgcn_global_load_lds(
        (const __attribute__((address_space(1))) unsigned int*)(uintptr_t)gptr,
        (__attribute__((address_space(3))) unsigned int*)(uint32_t)(uintptr_t)lptr,
        16, 0, 0);
}

// Fused fp32 -> bf16 convert for all three tensors, 8 elems/thread.
__global__ __launch_bounds__(256)
void cvt_all(const float* __restrict__ s1, bf16* __restrict__ d1, int n1,
             const float* __restrict__ s2, bf16* __restrict__ d2, int n2,
             const float* __restrict__ s3, bf16* __restrict__ d3, int n3) {
    int i = blockIdx.x * blockDim.x + threadIdx.x;
    const float* src; bf16* dst;
    if (i < n1)              { src = s1; dst = d1; }
    else if (i < n1 + n2)    { i -= n1; src = s2; dst = d2; }
    else if (i < n1+n2+n3)   { i -= n1 + n2; src = s3; dst = d3; }
    else return;
    const float4 a = ((const float4*)src)[2 * i];
    const float4 b = ((const float4*)src)[2 * i + 1];
    union { u16x8 v; __hip_bfloat16 h[8]; } o;
    o.h[0] = __float2bfloat16(a.x); o.h[1] = __float2bfloat16(a.y);
    o.h[2] = __float2bfloat16(a.z); o.h[3] = __float2bfloat16(a.w);
    o.h[4] = __float2bfloat16(b.x); o.h[5] = __float2bfloat16(b.y);
    o.h[6] = __float2bfloat16(b.z); o.h[7] = __float2bfloat16(b.w);
    ((u16x8*)dst)[i] = o.v;
}

// C = A[M,K] * B[N,K]^T + bias[N]. A,B bf16; bias fp32.
// QKV_LAYOUT=false: C[row][col] standard, OutT elems, leading dim NMAT.
// QKV_LAYOUT=true : C written as [b,h,s,t,d] bf16 (s=col>>10, h=(col>>6)&15, d=col&63;
//                   b=row>>11, t=row&2047). 16-col nt-groups never straddle a head.
template <int NMAT, typename OutT, bool QKV_LAYOUT>
__global__ __launch_bounds__(256)
void gemm_bt_bias(const bf16* __restrict__ A, const bf16* __restrict__ B,
                  const float* __restrict__ bias, OutT* __restrict__ C) {
    __shared__ bf16 As[128 * 64];   // 16 KB
    __shared__ bf16 Bs[128 * 64];   // 16 KB

    const int tid  = threadIdx.x;
    const int lane = tid & 63;
    const int wave = tid >> 6;
    const int quad = lane >> 4;
    const int l16  = lane & 15;

    const int tileM = blockIdx.y * 128;
    const int tileN = blockIdx.x * 128;
    const int wm = (wave >> 1) * 64;
    const int wn = (wave & 1) * 64;

    f32x4 acc[4][4] = {};

    for (int kt = 0; kt < KDIM; kt += 64) {
        // stage 128x64 tiles: LDS chunk c holds global chunk (c&7)^(row&7) of row c>>3.
        #pragma unroll
        for (int i = 0; i < 4; ++i) {
            const int c   = i * 256 + tid;
            const int row = c >> 3;
            const int kg  = (c & 7) ^ (row & 7);
            async_copy16(A + (size_t)(tileM + row) * KDIM + kt + kg * 8,
                         (char*)As + c * 16);
            async_copy16(B + (size_t)(tileN + row) * KDIM + kt + kg * 8,
                         (char*)Bs + c * 16);
        }
        __syncthreads();

        #pragma unroll
        for (int ks = 0; ks < 2; ++ks) {
            const int kq = ks * 4 + quad;
            const int so = (kq ^ (l16 & 7)) * 8;
            bf16x8 aF[4], bF[4];
            #pragma unroll
            for (int mt = 0; mt < 4; ++mt)
                aF[mt] = *(const bf16x8*)(As + (wm + mt * 16 + l16) * 64 + so);
            #pragma unroll
            for (int nt = 0; nt < 4; ++nt)
                bF[nt] = *(const bf16x8*)(Bs + (wn + nt * 16 + l16) * 64 + so);

            #pragma unroll
            for (int mt = 0; mt < 4; ++mt)
                #pragma unroll
                for (int nt = 0; nt < 4; ++nt)
                    acc[mt][nt] = __builtin_amdgcn_mfma_f32_16x16x32_bf16(
                        aF[mt], bF[nt], acc[mt][nt], 0, 0, 0);
        }
        __syncthreads();
    }

    // epilogue: C/D layout col = lane&15, row = quad*4 + reg  [m89/m91-verified]
    #pragma unroll
    for (int nt = 0; nt < 4; ++nt) {
        const int scol = tileN + wn + nt * 16;       // head-aligned 16-col group
        const float bv = bias[scol + l16];
        #pragma unroll
        for (int mt = 0; mt < 4; ++mt) {
            #pragma unroll
            for (int r = 0; r < 4; ++r) {
                const int rowg = tileM + wm + mt * 16 + quad * 4 + r;
                const float v = acc[mt][nt][r] + bv;
                if constexpr (QKV_LAYOUT) {
                    const int s = scol >> 10;
                    const int h = (scol >> 6) & (NHEAD - 1);
                    const int d = (scol & 63) + l16;
                    const int b = rowg >> 11;
                    const int t = rowg & (SEQ - 1);
                    ((bf16*)C)[(size_t)((b * NHEAD + h) * 3 + s) * HSLICE
                               + (size_t)t * HDIM + d] = __float2bfloat16(v);
                } else if constexpr (std::is_same<OutT, float>::value) {
                    C[(size_t)rowg * NMAT + scol + l16] = v;
                } else {
                    C[(size_t)rowg * NMAT + scol + l16] = __float2bfloat16(v);
                }
            }
        }
    }
}

// ---- 8 bf16 (as uint4) -> 8 floats (hi half = mask, lo half = shift)
__device__ __forceinline__ void bf8_to_f32(const uint4 u, float* f) {
    union { uint32_t u; float f; } c;
    c.u = u.x << 16;         f[0] = c.f;
    c.u = u.x & 0xffff0000u; f[1] = c.f;
    c.u = u.y << 16;         f[2] = c.f;
    c.u = u.y & 0xffff0000u; f[3] = c.f;
    c.u = u.z << 16;         f[4] = c.f;
    c.u = u.z & 0xffff0000u; f[5] = c.f;
    c.u = u.w << 16;         f[6] = c.f;
    c.u = u.w & 0xffff0000u; f[7] = c.f;
}

// Banded attention over [b,h,s,t,d] qkv. Block=256 covers 128 queries of one (b,h);
// tid = qi*2+hf, hf selects 32 dims. All reads are sequential 128-B rows per token.
__global__ __launch_bounds__(256)
void attn_banded3(const bf16* __restrict__ qkv, bf16* __restrict__ aout) {
    const int tid = threadIdx.x;
    const int qi  = tid >> 1;
    const int hf  = tid & 1;
    const int t0  = blockIdx.x * 128;
    const int h   = blockIdx.y;
    const int b   = blockIdx.z;
    const int t   = t0 + qi;

    const size_t bh3 = (size_t)(b * NHEAD + h) * 3;
    const bf16* qb = qkv + (bh3 + 0) * HSLICE + (size_t)t * HDIM + hf * 32;
    const bf16* kb = qkv + (bh3 + 1) * HSLICE + hf * 32;
    const bf16* vb = qkv + (bh3 + 2) * HSLICE + hf * 32;
    const float scale = 0.125f;   // hd^-0.5

    float q32[32];
    {
        const uint4* qp = (const uint4*)qb;
        uint4 u0 = qp[0], u1 = qp[1], u2 = qp[2], u3 = qp[3];
        bf8_to_f32(u0, q32 + 0);  bf8_to_f32(u1, q32 + 8);
        bf8_to_f32(u2, q32 + 16); bf8_to_f32(u3, q32 + 24);
    }

    float sc[2 * RADIUS + 1];
    #pragma unroll
    for (int j = 0; j < 2 * RADIUS + 1; ++j) {
        const int k = t - RADIUS + j;
        const bool valid = (k >= 0) && (k < SEQ);
        const int kc = valid ? k : t;
        const uint4* kp = (const uint4*)(kb + (size_t)kc * HDIM);
        float kf[32];
        uint4 u0 = kp[0], u1 = kp[1], u2 = kp[2], u3 = kp[3];
        bf8_to_f32(u0, kf + 0);  bf8_to_f32(u1, kf + 8);
        bf8_to_f32(u2, kf + 16); bf8_to_f32(u3, kf + 24);
        float p = 0.f;
        #pragma unroll
        for (int e = 0; e < 32; ++e) p = fmaf(q32[e], kf[e], p);
        p += __shfl_xor(p, 1, 64);          // merge the two 32-dim halves
        sc[j] = valid ? p * scale : -1e30f;
    }

    float mx = sc[0];
    #pragma unroll
    for (int j = 1; j < 2 * RADIUS + 1; ++j) mx = fmaxf(mx, sc[j]);
    float sum = 0.f;
    #pragma unroll
    for (int j = 0; j < 2 * RADIUS + 1; ++j) { sc[j] = __expf(sc[j] - mx); sum += sc[j]; }
    const float inv = 1.0f / sum;

    float o32[32];
    #pragma unroll
    for (int e = 0; e < 32; ++e) o32[e] = 0.f;
    #pragma unroll
    for (int j = 0; j < 2 * RADIUS + 1; ++j) {
        const int k = t - RADIUS + j;
        const int kc = (k >= 0 && k < SEQ) ? k : t;   // weight ~0 when clamped
        const uint4* vp = (const uint4*)(vb + (size_t)kc * HDIM);
        float vf[32];
        uint4 u0 = vp[0], u1 = vp[1], u2 = vp[2], u3 = vp[3];
        bf8_to_f32(u0, vf + 0);  bf8_to_f32(u1, vf + 8);
        bf8_to_f32(u2, vf + 16); bf8_to_f32(u3, vf + 24);
        const float w = sc[j];
        #pragma unroll
        for (int e = 0; e < 32; ++e) o32[e] = fmaf(w, vf[e], o32[e]);
    }

    // store in standard [token][1024] layout for GEMM2's A
    bf16* op = aout + ((size_t)b * SEQ + t) * DIM + h * HDIM + hf * 32;
    #pragma unroll
    for (int c = 0; c < 4; ++c) {
        union { u16x8 v; __hip_bfloat16 hh[8]; } o;
        #pragma unroll
        for (int e = 0; e < 8; ++e) o.hh[e] = __float2bfloat16(o32[c * 8 + e] * inv);
        ((u16x8*)op)[c] = o.v;
    }
}

extern "C" void kernel_launch(void* const* d_in, const int* in_sizes, int n_in,
                              void* d_out, int out_size, void* d_ws, size_t ws_size,
                              hipStream_t stream) {
    const float* x      = (const float*)d_in[0];
    const float* w_qkv  = (const float*)d_in[1];
    const float* b_qkv  = (const float*)d_in[2];
    const float* w_proj = (const float*)d_in[3];
    const float* b_proj = (const float*)d_in[4];
    float* out = (float*)d_out;

    bf16* xb     = (bf16*)d_ws;
    bf16* wqkvb  = xb + (size_t)ROWS * DIM;
    bf16* wprojb = wqkvb + (size_t)3072 * 1024;
    bf16* qkvb   = wprojb + (size_t)1024 * 1024;   // [b,h,s,t,d] layout, 48 MiB
    bf16* attnb  = qkvb + (size_t)ROWS * 3072;

    const int n1 = ROWS * DIM / 8, n2 = 3072 * 1024 / 8, n3 = 1024 * 1024 / 8;
    cvt_all<<<(n1 + n2 + n3 + 255) / 256, 256, 0, stream>>>(x, xb, n1, w_qkv, wqkvb, n2,
                                                            w_proj, wprojb, n3);

    // GEMM1 -> qkv in attention-native layout
    gemm_bt_bias<3072, bf16, true><<<dim3(3072 / 128, ROWS / 128), 256, 0, stream>>>(
        xb, wqkvb, b_qkv, qkvb);

    attn_banded3<<<dim3(SEQ / 128, NHEAD, BATCH), 256, 0, stream>>>(qkvb, attnb);

    gemm_bt_bias<1024, float, false><<<dim3(1024 / 128, ROWS / 128), 256, 0, stream>>>(
        attnb, wprojb, b_proj, out);
}